// Round 12
// baseline (164.601 us; speedup 1.0000x reference)
//
#include <hip/hip_runtime.h>

#define DD 512
#define MROWS 384            // 4 batches * 96 nodes
#define EPSF 1e-5f
#define INVN (1.0f / 96.0f)
#define NBLK 96              // 96 blocks x 1024 thr = 1536 waves, all co-resident
#define NGRP 12              // barrier: 12 groups of 8 blocks
#define BAR_OFF (16u << 20)  // barrier slots at ws+16MB (past all buffers)
#define NSLOT 6

typedef short short8v __attribute__((ext_vector_type(8)));
typedef float f32x4   __attribute__((ext_vector_type(4)));

// round-to-nearest-even f32 -> bf16 (raw ushort)
static __device__ __forceinline__ unsigned short f2bf(float x) {
    union { float f; unsigned int u; } v; v.f = x;
    unsigned int r = v.u + 0x7fffu + ((v.u >> 16) & 1u);
    return (unsigned short)(r >> 16);
}

struct GnnParams {
    const float *h0, *adj, *W1a, *W1b, *b1, *W2, *b2, *gamma, *beta;
    float *out;
    unsigned short *WT, *H0bf, *H1bf, *S0, *S1;
    float *A0, *B0, *A1, *B1, *H1, *CNT;
    unsigned int *bar;       // NSLOT slots x 64 uints (256B each), zeroed per replay
};

// Hierarchical grid barrier (slot used once per launch; memset re-zeroes).
// release: __threadfence() (agent fence: waitcnt + L2 writeback)  [R10-proven]
// acquire: __threadfence() (agent fence: L1/L2 invalidate)
static __device__ __forceinline__ void gbar(unsigned int* bar, int slot,
                                            int bid, int tid) {
    __syncthreads();                       // drains block's stores (vmcnt 0)
    if (tid == 0) {
        __threadfence();                   // release
        unsigned int* s = bar + slot * 64;
        const int g = bid >> 3;            // group of 8
        if (atomicAdd(&s[g], 1u) == 7u) {
            if (atomicAdd(&s[48], 1u) == (unsigned)(NGRP - 1)) {
                __threadfence();
                atomicExch(&s[56], 1u);    // release flag
            }
        }
        while (__hip_atomic_load(&s[56], __ATOMIC_RELAXED,
                                 __HIP_MEMORY_SCOPE_AGENT) == 0u)
            __builtin_amdgcn_s_sleep(8);
        __threadfence();                   // acquire
    }
    __syncthreads();
}

__global__ __launch_bounds__(1024) void gnn_fused(GnnParams P)
{
    const int tid  = threadIdx.x;
    const int bid  = blockIdx.x;
    const int lane = tid & 63;
    const int wv   = __builtin_amdgcn_readfirstlane(tid >> 6);  // 0..15
    const int gw   = bid * 16 + wv;                             // 0..1535

    __shared__ float tsh[32][33];     // 4.2 KB (transpose)
    __shared__ float Ush[16][516];    // 33 KB  (P34 U tile)

    // ---- P0a: transpose+convert 6 weight mats -> bf16 [n][k] (1536 tiles,
    //           16 per block; 1024 thr = 1 elem/thread of a 32x32 tile) ----
    {
        const int tx = tid & 31, ty = tid >> 5;   // ty 0..31
        for (int i = 0; i < 16; ++i) {
            const int it = bid * 16 + i;
            const int z  = it >> 8;
            const int r0 = ((it >> 4) & 15) * 32;
            const int c0 = (it & 15) * 32;
            const int l = z / 3, w = z % 3;
            const float* __restrict__ src =
                (w == 0 ? P.W1a : (w == 1 ? P.W1b : P.W2)) + (size_t)l * DD * DD;
            unsigned short* __restrict__ dst = P.WT + (size_t)z * DD * DD;
            tsh[ty][tx] = src[(size_t)(r0 + ty) * DD + c0 + tx];
            __syncthreads();
            dst[(size_t)(c0 + ty) * DD + r0 + tx] = f2bf(tsh[tx][ty]);
            __syncthreads();
        }
    }
    // ---- P0b: h0 -> bf16 (blocks 24..47; 24576 x 8-float items) ----
    if (bid >= 24 && bid < 48) {
        const int i = (bid - 24) * 1024 + tid;    // < 24576 always
        const float4 x0 = *(const float4*)(P.h0 + (size_t)i * 8);
        const float4 x1 = *(const float4*)(P.h0 + (size_t)i * 8 + 4);
        uint4 u;
        u.x = (unsigned)f2bf(x0.x) | ((unsigned)f2bf(x0.y) << 16);
        u.y = (unsigned)f2bf(x0.z) | ((unsigned)f2bf(x0.w) << 16);
        u.z = (unsigned)f2bf(x1.x) | ((unsigned)f2bf(x1.y) << 16);
        u.w = (unsigned)f2bf(x1.z) | ((unsigned)f2bf(x1.w) << 16);
        *(uint4*)(P.H0bf + (size_t)i * 8) = u;
    }
    // ---- P0c: cnt[r] = sum_j mask[r,j] (blocks 72..95, one wave/row) ----
    if (gw >= 1152) {
        const int r = gw - 1152;                  // 0..383
        const float* mrow = P.adj + (size_t)r * 96;
        float v = mrow[lane];
        if (lane < 32) v += mrow[64 + lane];
#pragma unroll
        for (int off = 32; off > 0; off >>= 1) v += __shfl_xor(v, off);
        if (lane == 0) P.CNT[r] = v;
    }
    gbar(P.bar, 0, bid, tid);

    for (int l = 0; l < 2; ++l) {
        const unsigned short* __restrict__ WaT = P.WT + (size_t)(l * 3 + 0) * DD * DD;
        const unsigned short* __restrict__ WbT = P.WT + (size_t)(l * 3 + 1) * DD * DD;
        const unsigned short* __restrict__ W2T = P.WT + (size_t)(l * 3 + 2) * DD * DD;
        const float* b1l = P.b1 + (size_t)l * DD;
        const float* b2l = P.b2 + (size_t)l * DD;
        const unsigned short* __restrict__ Hbf = l ? P.H1bf : P.H0bf;
        float* __restrict__ A  = l ? P.A1 : P.A0;
        float* __restrict__ Bb = l ? P.B1 : P.B0;
        unsigned short* __restrict__ S = l ? P.S1 : P.S0;
        const float* __restrict__ hin = l ? P.H1 : P.h0;
        float* __restrict__ hout = l ? P.out : P.H1;

        // ---- P1: A = Hbf@Wa + b1 ; Bb = Hbf@Wb (1536 wave-tiles) ----
        {
            const int isB = gw >= 768;
            const int t   = gw - (isB ? 768 : 0);   // R9 fix: 768 not pow2
            const int m0  = (t >> 5) * 16;
            const int n0  = (t & 31) * 16;
            const int lo = lane & 15, hi = lane >> 4;
            const unsigned short* ap = Hbf + (size_t)(m0 + lo) * DD + 8 * hi;
            const unsigned short* bp = (isB ? WbT : WaT) + (size_t)(n0 + lo) * DD + 8 * hi;
            f32x4 acc = {0.f, 0.f, 0.f, 0.f};
#pragma unroll
            for (int k0 = 0; k0 < DD; k0 += 32)
                acc = __builtin_amdgcn_mfma_f32_16x16x32_bf16(
                    *(const short8v*)(ap + k0), *(const short8v*)(bp + k0), acc, 0, 0, 0);
            const int col = n0 + lo;
            const float bias = isB ? 0.f : b1l[col];
            float* __restrict__ outp = isB ? Bb : A;
            const int rb = m0 + 4 * hi;
#pragma unroll
            for (int i = 0; i < 4; ++i)
                outp[(size_t)(rb + i) * DD + col] = acc[i] + bias;
        }
        gbar(P.bar, 1 + l * 3, bid, tid);

        // ---- P2: S[b,i,d] = sum_j mask*relu(A + Bb) -> bf16 (1536 units) ----
        {
            const int b   = gw / 384;
            const int rem = gw - b * 384;
            const int i0  = (rem >> 3) * 2;
            const int d   = (rem & 7) * 64 + lane;
            const int rb  = b * 96 + i0;
            const float a0 = A[(size_t)rb * DD + d];
            const float a1 = A[(size_t)(rb + 1) * DD + d];
            const float* __restrict__ mp  = P.adj + (size_t)rb * 96;
            const float* __restrict__ bbp = Bb + (size_t)b * 96 * DD + d;
            float s0 = 0.f, s1 = 0.f;
#pragma unroll 8
            for (int j = 0; j < 96; ++j) {
                const float bv = bbp[(size_t)j * DD];
                s0 = fmaf(mp[j],      fmaxf(a0 + bv, 0.f), s0);
                s1 = fmaf(mp[96 + j], fmaxf(a1 + bv, 0.f), s1);
            }
            S[(size_t)rb * DD + d]       = f2bf(s0);
            S[(size_t)(rb + 1) * DD + d] = f2bf(s1);
        }
        gbar(P.bar, 2 + l * 3, bid, tid);

        // ---- P34 (blocks 0..23): U(LDS) = hin + INVN*(S@W2 + cnt*b2),
        //      then in-block LayerNorm (+clip / +bf16 emit) ----
        if (bid < 24) {
            const int m0g = bid * 16;
            const int lo = lane & 15, hi = lane >> 4;
#pragma unroll
            for (int i = 0; i < 2; ++i) {
                const int n0 = (wv * 2 + i) * 16;
                const unsigned short* ap = S + (size_t)(m0g + lo) * DD + 8 * hi;
                const unsigned short* bp = W2T + (size_t)(n0 + lo) * DD + 8 * hi;
                f32x4 acc = {0.f, 0.f, 0.f, 0.f};
#pragma unroll 4
                for (int k0 = 0; k0 < DD; k0 += 32)
                    acc = __builtin_amdgcn_mfma_f32_16x16x32_bf16(
                        *(const short8v*)(ap + k0), *(const short8v*)(bp + k0), acc, 0, 0, 0);
                const int col = n0 + lo;
                const float b2c = b2l[col];
#pragma unroll
                for (int q = 0; q < 4; ++q) {
                    const int rr = 4 * hi + q;
                    Ush[rr][col] = hin[(size_t)(m0g + rr) * DD + col]
                                 + INVN * acc[q] + (P.CNT[m0g + rr] * INVN) * b2c;
                }
            }
            __syncthreads();
            // LayerNorm: wave wv -> row wv (shfl-only, R5/R10-proven math)
            {
                const int rr = wv;
                const int r  = m0g + rr;
                const float4 x0 = *(const float4*)&Ush[rr][lane * 8];
                const float4 x1 = *(const float4*)&Ush[rr][lane * 8 + 4];
                float s = x0.x + x0.y + x0.z + x0.w + x1.x + x1.y + x1.z + x1.w;
#pragma unroll
                for (int off = 32; off > 0; off >>= 1) s += __shfl_xor(s, off);
                const float mu = s * (1.0f / 512.0f);
                const float d0 = x0.x - mu, d1 = x0.y - mu, d2 = x0.z - mu, d3 = x0.w - mu;
                const float d4 = x1.x - mu, d5 = x1.y - mu, d6 = x1.z - mu, d7 = x1.w - mu;
                float q = d0*d0 + d1*d1 + d2*d2 + d3*d3 + d4*d4 + d5*d5 + d6*d6 + d7*d7;
#pragma unroll
                for (int off = 32; off > 0; off >>= 1) q += __shfl_xor(q, off);
                const float rs = rsqrtf(q * (1.0f / 512.0f) + EPSF);

                const float4 g0 = *(const float4*)(P.gamma + lane * 8);
                const float4 g1 = *(const float4*)(P.gamma + lane * 8 + 4);
                const float4 t0 = *(const float4*)(P.beta + lane * 8);
                const float4 t1 = *(const float4*)(P.beta + lane * 8 + 4);
                float y0 = d0*rs*g0.x + t0.x, y1 = d1*rs*g0.y + t0.y;
                float y2 = d2*rs*g0.z + t0.z, y3 = d3*rs*g0.w + t0.w;
                float y4 = d4*rs*g1.x + t1.x, y5 = d5*rs*g1.y + t1.y;
                float y6 = d6*rs*g1.z + t1.z, y7 = d7*rs*g1.w + t1.w;
                if (l == 1) {
                    y0 = fminf(fmaxf(y0, -100.f), 100.f); y1 = fminf(fmaxf(y1, -100.f), 100.f);
                    y2 = fminf(fmaxf(y2, -100.f), 100.f); y3 = fminf(fmaxf(y3, -100.f), 100.f);
                    y4 = fminf(fmaxf(y4, -100.f), 100.f); y5 = fminf(fmaxf(y5, -100.f), 100.f);
                    y6 = fminf(fmaxf(y6, -100.f), 100.f); y7 = fminf(fmaxf(y7, -100.f), 100.f);
                }
                float4 o0 = {y0, y1, y2, y3}, o1 = {y4, y5, y6, y7};
                *(float4*)(hout + (size_t)r * DD + lane * 8)     = o0;
                *(float4*)(hout + (size_t)r * DD + lane * 8 + 4) = o1;
                if (l == 0) {
                    uint4 u;
                    u.x = (unsigned)f2bf(y0) | ((unsigned)f2bf(y1) << 16);
                    u.y = (unsigned)f2bf(y2) | ((unsigned)f2bf(y3) << 16);
                    u.z = (unsigned)f2bf(y4) | ((unsigned)f2bf(y5) << 16);
                    u.w = (unsigned)f2bf(y6) | ((unsigned)f2bf(y7) << 16);
                    *(uint4*)(P.H1bf + (size_t)r * DD + lane * 8) = u;
                }
            }
        }
        if (l == 0) gbar(P.bar, 3, bid, tid);
    }
}

// ---------------------------------------------------------------------------
extern "C" void kernel_launch(void* const* d_in, const int* in_sizes, int n_in,
                              void* d_out, int out_size, void* d_ws, size_t ws_size,
                              hipStream_t stream)
{
    GnnParams prm;
    prm.h0    = (const float*)d_in[0];   // (4,96,512)
    prm.adj   = (const float*)d_in[1];   // (4,96,96)
    prm.W1a   = (const float*)d_in[2];   // (2,512,512)
    prm.W1b   = (const float*)d_in[3];   // (2,512,512)
    prm.b1    = (const float*)d_in[4];   // (2,512)
    prm.W2    = (const float*)d_in[5];   // (2,512,512)
    prm.b2    = (const float*)d_in[6];   // (2,512)
    prm.gamma = (const float*)d_in[7];   // (512)
    prm.beta  = (const float*)d_in[8];   // (512)
    prm.out   = (float*)d_out;           // (4,96,512)

    char* p = (char*)d_ws;
    prm.WT   = (unsigned short*)p;  p += 6u * DD * DD * 2;   // 3.00 MB
    prm.H0bf = (unsigned short*)p;  p += MROWS * DD * 2;     // 384 KB
    prm.H1bf = (unsigned short*)p;  p += MROWS * DD * 2;     // 384 KB
    prm.S0   = (unsigned short*)p;  p += MROWS * DD * 2;     // 384 KB
    prm.S1   = (unsigned short*)p;  p += MROWS * DD * 2;     // 384 KB
    prm.A0   = (float*)p;           p += MROWS * DD * 4;     // 768 KB
    prm.B0   = (float*)p;           p += MROWS * DD * 4;     // 768 KB
    prm.A1   = (float*)p;           p += MROWS * DD * 4;     // 768 KB
    prm.B1   = (float*)p;           p += MROWS * DD * 4;     // 768 KB
    prm.H1   = (float*)p;           p += MROWS * DD * 4;     // 768 KB
    prm.CNT  = (float*)p;                                    // 1.5 KB
    prm.bar  = (unsigned int*)((char*)d_ws + BAR_OFF);       // 6 x 256 B slots

    // re-zero barrier slots on every replay (graph memset node, allowed op)
    hipMemsetAsync((void*)prm.bar, 0, NSLOT * 256, stream);

    void* args[] = { (void*)&prm };
    hipLaunchKernel((const void*)gnn_fused, dim3(NBLK), dim3(1024),
                    args, 0, stream);
}

// Round 13
// 112.846 us; speedup vs baseline: 1.4586x; 1.4586x over previous
//
#include <hip/hip_runtime.h>

#define DD 512
#define MROWS 384            // 4 batches * 96 nodes
#define EPSF 1e-5f
#define INVN (1.0f / 96.0f)

typedef short short8v __attribute__((ext_vector_type(8)));
typedef float f32x4   __attribute__((ext_vector_type(4)));

// round-to-nearest-even f32 -> bf16 (raw ushort)
static __device__ __forceinline__ unsigned short f2bf(float x) {
    union { float f; unsigned int u; } v; v.f = x;
    unsigned int r = v.u + 0x7fffu + ((v.u >> 16) & 1u);
    return (unsigned short)(r >> 16);
}

// ---------------------------------------------------------------------------
// K1 (R7-proven verbatim): z=0..5 -> transpose+convert weight mat z (l=z/3,
// {W1a,W1b,W2}) into WT[z] as bf16 [n][k]. z==6: y<12 -> h0->bf16;
// y==12 -> cnt[r] = sum_j adj[r,j]. grid (16,16,7), block (32,8).
// ---------------------------------------------------------------------------
__global__ __launch_bounds__(256) void convert_all(
    const float* __restrict__ W1a, const float* __restrict__ W1b,
    const float* __restrict__ W2, const float* __restrict__ h0,
    const float* __restrict__ adj,
    unsigned short* __restrict__ WT, unsigned short* __restrict__ Hbf,
    float* __restrict__ CNT)
{
    const int tx = threadIdx.x, ty = threadIdx.y;
    const int z  = blockIdx.z;
    const int c0 = blockIdx.x * 32, r0 = blockIdx.y * 32;

    if (z == 6) {
        if (blockIdx.y < 12) {                    // h0 -> bf16 (384x512)
#pragma unroll
            for (int i = 0; i < 4; ++i) {
                const int r = r0 + ty + 8 * i;
                Hbf[(size_t)r * DD + c0 + tx] = f2bf(h0[(size_t)r * DD + c0 + tx]);
            }
        } else if (blockIdx.y == 12) {            // cnt: 16 blocks * 4 waves * 6 rows
            const int tid  = ty * 32 + tx;
            const int lane = tid & 63;
            const int wv   = tid >> 6;
            const int rb   = (blockIdx.x * 4 + wv) * 6;
#pragma unroll
            for (int q = 0; q < 6; ++q) {
                const float* mrow = adj + (size_t)(rb + q) * 96;
                float v = mrow[lane];
                if (lane < 32) v += mrow[64 + lane];
#pragma unroll
                for (int off = 32; off > 0; off >>= 1) v += __shfl_xor(v, off);
                if (lane == 0) CNT[rb + q] = v;
            }
        }
        return;
    }

    __shared__ float t[32][33];
    const int l = z / 3, w = z % 3;
    const float* __restrict__ src =
        (w == 0 ? W1a : (w == 1 ? W1b : W2)) + (size_t)l * DD * DD;
    unsigned short* __restrict__ dst = WT + (size_t)z * DD * DD;

#pragma unroll
    for (int i = 0; i < 4; ++i)
        t[ty + 8 * i][tx] = src[(size_t)(r0 + ty + 8 * i) * DD + c0 + tx];
    __syncthreads();
#pragma unroll
    for (int i = 0; i < 4; ++i)
        dst[(size_t)(c0 + ty + 8 * i) * DD + r0 + tx] = f2bf(t[tx][ty + 8 * i]);
}

// ---------------------------------------------------------------------------
// K2 fused_front (per layer): block = (batch b, 16-col d-slice). 128 blocks.
//   (1) in-block GEMM: As[96][16] = Hbf[b]@WaT[:,d-slice] + b1 (LDS),
//       Bs likewise (no bias). 12 16x16 tiles / 4 waves, R5-proven frag math.
//   (2) relusum: S[b,i,d] = sum_j adj*relu(As[i]+Bs[j]) -> bf16 global.
// No A/Bb global round-trip; relusum spread over 128 CUs.
// ---------------------------------------------------------------------------
__global__ __launch_bounds__(256) void fused_front(
    const unsigned short* __restrict__ Hbf,
    const unsigned short* __restrict__ WaT,
    const unsigned short* __restrict__ WbT,
    const float* __restrict__ b1l, const float* __restrict__ adj,
    unsigned short* __restrict__ S)
{
    __shared__ float As[96][17];     // 6.4 KB (17-pad: conflict-free)
    __shared__ float Bs[96][17];     // 6.4 KB
    __shared__ float msk[96][97];    // 36.4 KB (97-pad: bank = row+col+q)

    const int tid = threadIdx.x;
    const int b   = blockIdx.x;
    const int d0  = blockIdx.y * 16;

    // stage adj[b] (9216 floats, coalesced rows into 97-stride LDS)
    const float* __restrict__ ab = adj + (size_t)b * 96 * 96;
    for (int t = tid; t < 96 * 96; t += 256)
        msk[t / 96][t % 96] = ab[t];

    // in-block GEMM: 12 tiles (6 m-tiles x {A,B}), wave w -> tiles 3w..3w+2
    const int lane = tid & 63;
    const int w    = tid >> 6;
    const int lo = lane & 15, hi = lane >> 4;
    const float b1v = b1l[d0 + lo];

#pragma unroll
    for (int s = 0; s < 3; ++s) {
        const int t   = w * 3 + s;            // 0..11
        const int isB = t >= 6;
        const int mt  = t - (isB ? 6 : 0);    // 0..5
        const unsigned short* ap = Hbf + (size_t)(b * 96 + mt * 16 + lo) * DD + 8 * hi;
        const unsigned short* bp = (isB ? WbT : WaT) + (size_t)(d0 + lo) * DD + 8 * hi;
        f32x4 acc = {0.f, 0.f, 0.f, 0.f};
#pragma unroll 4
        for (int k0 = 0; k0 < DD; k0 += 32)
            acc = __builtin_amdgcn_mfma_f32_16x16x32_bf16(
                *(const short8v*)(ap + k0), *(const short8v*)(bp + k0), acc, 0, 0, 0);
        const float bias = isB ? 0.f : b1v;
        float (* __restrict__ dst)[17] = isB ? Bs : As;
        const int rb = mt * 16 + 4 * hi;
#pragma unroll
        for (int q = 0; q < 4; ++q)
            dst[rb + q][lo] = acc[q] + bias;
    }
    __syncthreads();

    // relusum: thread = (i-group of 6 rows, col dd)
    const int dd = tid & 15;
    const int ig = tid >> 4;                  // 0..15
    const int i0 = ig * 6;
    float a6[6], s6[6];
#pragma unroll
    for (int q = 0; q < 6; ++q) { a6[q] = As[i0 + q][dd]; s6[q] = 0.f; }
#pragma unroll 4
    for (int j = 0; j < 96; ++j) {
        const float bv = Bs[j][dd];
#pragma unroll
        for (int q = 0; q < 6; ++q)
            s6[q] = fmaf(msk[i0 + q][j], fmaxf(a6[q] + bv, 0.f), s6[q]);
    }
#pragma unroll
    for (int q = 0; q < 6; ++q)
        S[(size_t)(b * 96 + i0 + q) * DD + d0 + dd] = f2bf(s6[q]);
}

// ---------------------------------------------------------------------------
// K3 fused_back (per layer): block = 16 rows x all 512 cols. grid 24.
//   U(LDS) = hin + INVN*(S@W2 + cnt*b2); then per-wave LayerNorm
//   (+ optional clip, + optional bf16 emit). R5 gemm_msg frags + R11 LN.
// ---------------------------------------------------------------------------
__global__ __launch_bounds__(1024) void fused_back(
    const unsigned short* __restrict__ S,
    const unsigned short* __restrict__ W2T,
    const float* __restrict__ b2l, const float* __restrict__ cnt,
    const float* __restrict__ hin, const float* __restrict__ gamma,
    const float* __restrict__ beta, float* __restrict__ hout,
    unsigned short* __restrict__ hbf_out, int doClip)
{
    __shared__ float Ush[16][516];   // 33 KB

    const int tid  = threadIdx.x;
    const int m0   = blockIdx.x * 16;
    const int lane = tid & 63;
    const int wv   = tid >> 6;
    const int lo = lane & 15, hi = lane >> 4;

#pragma unroll
    for (int i = 0; i < 2; ++i) {
        const int n0 = (wv * 2 + i) * 16;
        const unsigned short* ap = S + (size_t)(m0 + lo) * DD + 8 * hi;
        const unsigned short* bp = W2T + (size_t)(n0 + lo) * DD + 8 * hi;
        f32x4 acc = {0.f, 0.f, 0.f, 0.f};
#pragma unroll 4
        for (int k0 = 0; k0 < DD; k0 += 32)
            acc = __builtin_amdgcn_mfma_f32_16x16x32_bf16(
                *(const short8v*)(ap + k0), *(const short8v*)(bp + k0), acc, 0, 0, 0);
        const int col = n0 + lo;
        const float b2c = b2l[col];
#pragma unroll
        for (int q = 0; q < 4; ++q) {
            const int rr = 4 * hi + q;
            Ush[rr][col] = hin[(size_t)(m0 + rr) * DD + col]
                         + INVN * acc[q] + (cnt[m0 + rr] * INVN) * b2c;
        }
    }
    __syncthreads();

    // LayerNorm: wave wv -> row wv (shfl-only, R5/R11-proven math)
    {
        const int rr = wv;
        const int r  = m0 + rr;
        const float4 x0 = *(const float4*)&Ush[rr][lane * 8];
        const float4 x1 = *(const float4*)&Ush[rr][lane * 8 + 4];
        float s = x0.x + x0.y + x0.z + x0.w + x1.x + x1.y + x1.z + x1.w;
#pragma unroll
        for (int off = 32; off > 0; off >>= 1) s += __shfl_xor(s, off);
        const float mu = s * (1.0f / 512.0f);
        const float d0 = x0.x - mu, d1 = x0.y - mu, d2 = x0.z - mu, d3 = x0.w - mu;
        const float d4 = x1.x - mu, d5 = x1.y - mu, d6 = x1.z - mu, d7 = x1.w - mu;
        float q = d0*d0 + d1*d1 + d2*d2 + d3*d3 + d4*d4 + d5*d5 + d6*d6 + d7*d7;
#pragma unroll
        for (int off = 32; off > 0; off >>= 1) q += __shfl_xor(q, off);
        const float rs = rsqrtf(q * (1.0f / 512.0f) + EPSF);

        const float4 g0 = *(const float4*)(gamma + lane * 8);
        const float4 g1 = *(const float4*)(gamma + lane * 8 + 4);
        const float4 t0 = *(const float4*)(beta + lane * 8);
        const float4 t1 = *(const float4*)(beta + lane * 8 + 4);
        float y0 = d0*rs*g0.x + t0.x, y1 = d1*rs*g0.y + t0.y;
        float y2 = d2*rs*g0.z + t0.z, y3 = d3*rs*g0.w + t0.w;
        float y4 = d4*rs*g1.x + t1.x, y5 = d5*rs*g1.y + t1.y;
        float y6 = d6*rs*g1.z + t1.z, y7 = d7*rs*g1.w + t1.w;
        if (doClip) {
            y0 = fminf(fmaxf(y0, -100.f), 100.f); y1 = fminf(fmaxf(y1, -100.f), 100.f);
            y2 = fminf(fmaxf(y2, -100.f), 100.f); y3 = fminf(fmaxf(y3, -100.f), 100.f);
            y4 = fminf(fmaxf(y4, -100.f), 100.f); y5 = fminf(fmaxf(y5, -100.f), 100.f);
            y6 = fminf(fmaxf(y6, -100.f), 100.f); y7 = fminf(fmaxf(y7, -100.f), 100.f);
        }
        float4 o0 = {y0, y1, y2, y3}, o1 = {y4, y5, y6, y7};
        *(float4*)(hout + (size_t)r * DD + lane * 8)     = o0;
        *(float4*)(hout + (size_t)r * DD + lane * 8 + 4) = o1;
        if (hbf_out) {
            uint4 u;
            u.x = (unsigned)f2bf(y0) | ((unsigned)f2bf(y1) << 16);
            u.y = (unsigned)f2bf(y2) | ((unsigned)f2bf(y3) << 16);
            u.z = (unsigned)f2bf(y4) | ((unsigned)f2bf(y5) << 16);
            u.w = (unsigned)f2bf(y6) | ((unsigned)f2bf(y7) << 16);
            *(uint4*)(hbf_out + (size_t)r * DD + lane * 8) = u;
        }
    }
}

// ---------------------------------------------------------------------------
extern "C" void kernel_launch(void* const* d_in, const int* in_sizes, int n_in,
                              void* d_out, int out_size, void* d_ws, size_t ws_size,
                              hipStream_t stream)
{
    const float* h0    = (const float*)d_in[0];  // (4,96,512)
    const float* adj   = (const float*)d_in[1];  // (4,96,96)
    const float* W1a   = (const float*)d_in[2];  // (2,512,512)
    const float* W1b   = (const float*)d_in[3];  // (2,512,512)
    const float* b1    = (const float*)d_in[4];  // (2,512)
    const float* W2    = (const float*)d_in[5];  // (2,512,512)
    const float* b2    = (const float*)d_in[6];  // (2,512)
    const float* gamma = (const float*)d_in[7];  // (512)
    const float* beta  = (const float*)d_in[8];  // (512)
    float* out = (float*)d_out;                  // (4,96,512)

    char* p = (char*)d_ws;
    unsigned short* WT   = (unsigned short*)p;  p += 6u * DD * DD * 2;  // 3.00 MB
    unsigned short* H0bf = (unsigned short*)p;  p += MROWS * DD * 2;    // 384 KB
    unsigned short* H1bf = (unsigned short*)p;  p += MROWS * DD * 2;    // 384 KB
    unsigned short* S    = (unsigned short*)p;  p += MROWS * DD * 2;    // 384 KB
    float* H1  = (float*)p;  p += MROWS * DD * 4;                       // 768 KB
    float* CNT = (float*)p;                                             // 1.5 KB

    convert_all<<<dim3(16, 16, 7), dim3(32, 8), 0, stream>>>(
        W1a, W1b, W2, h0, adj, WT, H0bf, CNT);

    for (int l = 0; l < 2; ++l) {
        const unsigned short* waT = WT + (size_t)(l * 3 + 0) * DD * DD;
        const unsigned short* wbT = WT + (size_t)(l * 3 + 1) * DD * DD;
        const unsigned short* w2T = WT + (size_t)(l * 3 + 2) * DD * DD;
        const unsigned short* xbf = (l == 0) ? H0bf : H1bf;
        const float* hin = (l == 0) ? h0 : H1;
        float* hout = (l == 0) ? H1 : out;
        unsigned short* hbf_next = (l == 0) ? H1bf : nullptr;

        fused_front<<<dim3(4, 32), 256, 0, stream>>>(
            xbf, waT, wbT, b1 + (size_t)l * DD, adj, S);
        fused_back<<<dim3(24), 1024, 0, stream>>>(
            S, w2T, b2 + (size_t)l * DD, CNT, hin, gamma, beta, hout,
            hbf_next, l == 1);
    }
}